// Round 10
// baseline (1707.253 us; speedup 1.0000x reference)
//
#include <hip/hip_runtime.h>

#define NEG_INF_VAL -1000000.0f

typedef short s16x8 __attribute__((ext_vector_type(8)));
typedef float f32x4 __attribute__((ext_vector_type(4)));

__device__ __forceinline__ unsigned int bf16_rne(float f) {
  unsigned int u = __float_as_uint(f);
  return (u + 0x7fffu + ((u >> 16) & 1u)) >> 16;
}
__device__ __forceinline__ unsigned int pack_bf2(float a, float b) {
  return bf16_rne(a) | (bf16_rne(b) << 16);
}

// tanh(x) = 1 - 2/(e^2x + 1); saturates correctly for |x| large.
__device__ __forceinline__ float fast_tanh(float x) {
  float t = __expf(2.f * x);
  return 1.f - __fdividef(2.f, t + 1.f);
}

// ---------------- K1: fp32 -> bf16 convert (vectorized, grid-stride) ---------
__global__ __launch_bounds__(256) void convert_bf16_kernel(
    const float* __restrict__ src, unsigned short* __restrict__ dst, long n) {
  long i = ((long)blockIdx.x * blockDim.x + threadIdx.x) * 8;
  long stride = (long)gridDim.x * blockDim.x * 8;
  for (; i < n; i += stride) {
    float4 f0 = *(const float4*)(src + i);
    float4 f1 = *(const float4*)(src + i + 4);
    uint4 o;
    o.x = pack_bf2(f0.x, f0.y);
    o.y = pack_bf2(f0.z, f0.w);
    o.z = pack_bf2(f1.x, f1.y);
    o.w = pack_bf2(f1.z, f1.w);
    *(uint4*)(dst + i) = o;
  }
}

// ---------------- K2: targetT[b,d] = sum_q input[b,q] * W_q[d,q] -------------
__global__ __launch_bounds__(256) void targetT_kernel(
    const float* __restrict__ input, const float* __restrict__ Wq,
    float* __restrict__ tT) {
  int d0 = blockIdx.x * 8;
  int t = threadIdx.x;
  int b = t >> 3, dl = t & 7;
  __shared__ float in_s[32][32];
  __shared__ float wq_s[8][32];
  float acc = 0.f;
  for (int q0 = 0; q0 < 1024; q0 += 32) {
    int r = t >> 3, c = (t & 7) * 4;
    *(float4*)&in_s[r][c] = *(const float4*)&input[r * 1024 + q0 + c];
    wq_s[t >> 5][t & 31] = Wq[(long)(d0 + (t >> 5)) * 1024 + q0 + (t & 31)];
    __syncthreads();
#pragma unroll
    for (int qq = 0; qq < 32; ++qq)
      acc += in_s[b][qq] * wq_s[dl][qq];
    __syncthreads();
  }
  tT[b * 1024 + d0 + dl] = acc;
}

// ---------------- K3: big GEMM + fused bias/tanh/energy-partial epilogue -----
// C[m,d] = sum_a ctx_bf16[m,a] * Wpre_bf16[d,a]  (NT GEMM)
// 256x256 tile, BK=32, 8 waves (2Mx4N, wave-tile 128x64), LDS 64 KiB ->
// 2 BLOCKS/CU. The per-tile vmcnt(0) drain + barrier serializes LDS reads and
// MFMA *within* a block (measured: all intra-block schedules ~equal); the
// SIBLING block on the CU, on its own barrier schedule, fills those stalls
// (m114 MFMA/VALU co-scheduling). Tile kept at 256^2 so per-barrier MFMA
// density and L2 reuse match R8 (R9's regression came from the 128^2 tile).
__device__ __forceinline__ void load_lds16(const void* g, void* l) {
  __builtin_amdgcn_global_load_lds(
      (const __attribute__((address_space(1))) void*)g,
      (__attribute__((address_space(3))) void*)l, 16, 0, 0);
}

// Stage A+B granules ([256 rows][32 cols] bf16 each) of K-tile SKT into buf SB.
#define STAGE_T(SB, SKT)                                                             \
  {                                                                                  \
    const unsigned short* gpA = Ag + (SKT) * 32;                                     \
    const unsigned short* gpB = Bg + (SKT) * 32;                                     \
    char* lp = dstB + (SB) * 32768;                                                  \
    load_lds16(gpA, lp);                                                             \
    load_lds16(gpA + 128L * 1024, lp + 8192);                                        \
    load_lds16(gpB, lp + 16384);                                                     \
    load_lds16(gpB + 128L * 1024, lp + 16384 + 8192);                                \
  }

#define MFMA_ROW(I, AF)                                                              \
  acc[I][0] = __builtin_amdgcn_mfma_f32_16x16x32_bf16(AF, bf[0], acc[I][0], 0, 0, 0);\
  acc[I][1] = __builtin_amdgcn_mfma_f32_16x16x32_bf16(AF, bf[1], acc[I][1], 0, 0, 0);\
  acc[I][2] = __builtin_amdgcn_mfma_f32_16x16x32_bf16(AF, bf[2], acc[I][2], 0, 0, 0);\
  acc[I][3] = __builtin_amdgcn_mfma_f32_16x16x32_bf16(AF, bf[3], acc[I][3], 0, 0, 0);

// One K-tile: read 8 A-frags + 4 B-frags from buf BUF, stage tile SKT into
// buf SB, 32 MFMA, drain DMA, barrier.
#define TILE(BUF, SB, SKT)                                                           \
  {                                                                                  \
    const unsigned short* pA = (BUF) ? pA1 : pA0;                                    \
    const unsigned short* pB = (BUF) ? pB1 : pB0;                                    \
    s16x8 af[8], bf[4];                                                              \
    _Pragma("unroll")                                                                \
    for (int i = 0; i < 8; ++i) af[i] = *(const s16x8*)(pA + i * 512);               \
    _Pragma("unroll")                                                                \
    for (int j = 0; j < 4; ++j) bf[j] = *(const s16x8*)(pB + j * 512);               \
    STAGE_T(SB, SKT)                                                                 \
    __builtin_amdgcn_s_setprio(1);                                                   \
    MFMA_ROW(0, af[0]) MFMA_ROW(1, af[1]) MFMA_ROW(2, af[2]) MFMA_ROW(3, af[3])      \
    MFMA_ROW(4, af[4]) MFMA_ROW(5, af[5]) MFMA_ROW(6, af[6]) MFMA_ROW(7, af[7])      \
    __builtin_amdgcn_s_setprio(0);                                                   \
    asm volatile("s_waitcnt vmcnt(0)");                                              \
    __builtin_amdgcn_sched_barrier(0);                                               \
    __builtin_amdgcn_s_barrier();                                                    \
  }

__global__ __launch_bounds__(512, 4) void gemm_energy_kernel(
    const unsigned short* __restrict__ A,   // [65536][1024] bf16
    const unsigned short* __restrict__ Bm,  // [1024][1024] bf16 (W_pre, N x K)
    const float* __restrict__ b_pre,        // [1024]
    const float* __restrict__ tT,           // [32][1024]
    const float* __restrict__ vvec,         // [1024]
    float* __restrict__ Cout,               // precompute [65536][1024] fp32
    float* __restrict__ epart) {            // [65536][16] fp32 partial energies
  // XCD-aware swizzle: nwg=1024 (%8==0); nt fastest within an XCD chunk.
  int lin = blockIdx.x;
  int w = (lin & 7) * 128 + (lin >> 3);
  int nt = w & 3;
  int mt = w >> 2;
  int m0 = mt * 256, n0 = nt * 256;
  int tid = threadIdx.x;
  int lane = tid & 63, wid = tid >> 6;     // 8 waves
  int wr = wid >> 2, wc = wid & 3;         // 2 x 4
  int r = lane & 15, g = lane >> 4;

  // flat LDS: [buf][mat][256 rows][32 cols] bf16 = 64 KiB
  // element strides: buf 16384, mat 8192
  __shared__ unsigned short sMem[2 * 2 * 256 * 32];

  f32x4 acc[8][4] = {};

  // read-side swizzled 16B slot (element offset): phys = g ^ ((r>>1)&3)
  int physoff = (g ^ ((r >> 1) & 3)) * 8;

  // LDS read bases; per-tile frag offsets are compile-time immediates.
  int aoffe = (wr * 128 + r) * 32 + physoff;
  int boffe = (wc * 64 + r) * 32 + physoff;
  const unsigned short* pA0 = sMem + aoffe;
  const unsigned short* pB0 = sMem + 8192 + boffe;
  const unsigned short* pA1 = sMem + 16384 + aoffe;
  const unsigned short* pB1 = sMem + 24576 + boffe;
  char* dstB = (char*)sMem + wid * 1024;   // linear gload_lds dest slice

  // staging source: thread covers rows {tid>>2, tid>>2+128}; global col
  // pre-swizzled: physical slot (tid&3) holds logical (tid&3)^((tid>>3)&3).
  int srow = tid >> 2;
  int slog8 = ((tid & 3) ^ ((tid >> 3) & 3)) * 8;
  const unsigned short* Ag = A + (long)(m0 + srow) * 1024 + slog8;
  const unsigned short* Bg = Bm + (long)(n0 + srow) * 1024 + slog8;

  // ---- prologue: buf0 = tile 0 ----
  STAGE_T(0, 0)
  asm volatile("s_waitcnt vmcnt(0)");
  __builtin_amdgcn_sched_barrier(0);
  __builtin_amdgcn_s_barrier();

  // ---- main loop: 32 K-tiles, 2 per iter (literal buf indices) ----
#pragma unroll 1
  for (int t0 = 0; t0 < 30; t0 += 2) {
    TILE(0, 1, t0 + 1)   // compute tile t0 (buf0); stage t0+1 -> buf1
    TILE(1, 0, t0 + 2)   // compute tile t0+1 (buf1); stage t0+2 -> buf0
  }
  TILE(0, 1, 31)         // compute tile 30; stage tile 31 -> buf1
  TILE(1, 0, 31)         // compute tile 31; re-stage 31 -> buf0 (unused, in-bounds)

  // ---- epilogue: C = acc + b_pre; energy partial = sum_d tanh(C+tT)*v ----
  int b = m0 >> 11;  // 256 | 2048 -> batch uniform per block
  float bias[4], tv[4], vv[4];
#pragma unroll
  for (int j = 0; j < 4; ++j) {
    int d = n0 + wc * 64 + j * 16 + r;
    bias[j] = b_pre[d];
    tv[j] = tT[b * 1024 + d];
    vv[j] = vvec[d];
  }
#pragma unroll
  for (int i = 0; i < 8; ++i) {
#pragma unroll
    for (int q = 0; q < 4; ++q) {
      int m = m0 + wr * 128 + i * 16 + g * 4 + q;
      float e = 0.f;
#pragma unroll
      for (int j = 0; j < 4; ++j) {
        float val = acc[i][j][q] + bias[j];
        Cout[(long)m * 1024 + n0 + wc * 64 + j * 16 + r] = val;
        e += fast_tanh(val + tv[j]) * vv[j];
      }
      e += __shfl_xor(e, 1);
      e += __shfl_xor(e, 2);
      e += __shfl_xor(e, 4);
      e += __shfl_xor(e, 8);
      if (r == 0) epart[(long)m * 16 + nt * 4 + wc] = e;
    }
  }
}

// ---------------- K4: reduce partials, mask, softmax over S ------------------
__global__ __launch_bounds__(256) void softmax_kernel(
    const float* __restrict__ epart, const int* __restrict__ mask,
    float* __restrict__ score) {
  int b = blockIdx.x;
  int t = threadIdx.x;
  __shared__ float red[256];
  float ev[8];
  float mx = -3.4e38f;
#pragma unroll
  for (int ii = 0; ii < 8; ++ii) {
    int s = ii * 256 + t;
    long m = (long)b * 2048 + s;
    const float4* p = (const float4*)(epart + m * 16);
    float4 p0 = p[0], p1 = p[1], p2 = p[2], p3 = p[3];
    float e = p0.x + p0.y + p0.z + p0.w + p1.x + p1.y + p1.z + p1.w
            + p2.x + p2.y + p2.z + p2.w + p3.x + p3.y + p3.z + p3.w;
    if (mask[b * 2048 + s] == 0) e = NEG_INF_VAL;
    ev[ii] = e;
    mx = fmaxf(mx, e);
  }
  red[t] = mx; __syncthreads();
  for (int off = 128; off > 0; off >>= 1) {
    if (t < off) red[t] = fmaxf(red[t], red[t + off]);
    __syncthreads();
  }
  mx = red[0];
  __syncthreads();
  float sum = 0.f;
#pragma unroll
  for (int ii = 0; ii < 8; ++ii) { ev[ii] = __expf(ev[ii] - mx); sum += ev[ii]; }
  red[t] = sum; __syncthreads();
  for (int off = 128; off > 0; off >>= 1) {
    if (t < off) red[t] += red[t + off];
    __syncthreads();
  }
  float inv = 1.f / red[0];
#pragma unroll
  for (int ii = 0; ii < 8; ++ii)
    score[b * 2048 + ii * 256 + t] = ev[ii] * inv;
}

// ---------------- K5: weightedContext partials over s-chunks -----------------
// Masked rows have score EXACTLY 0 (exp underflow) -> skip their 2KB read.
// wgt is uniform across the block for a given s => wave-uniform branch.
__global__ __launch_bounds__(256) void wc_partial_kernel(
    const unsigned short* __restrict__ ctx, const float* __restrict__ score,
    float* __restrict__ part) {
  int b = blockIdx.x, sc = blockIdx.y;
  int t = threadIdx.x;
  __shared__ float ssc[64];
  if (t < 64) ssc[t] = score[b * 2048 + sc * 64 + t];
  __syncthreads();
  float acc0 = 0.f, acc1 = 0.f, acc2 = 0.f, acc3 = 0.f;
  const unsigned short* cp0 = ctx + ((long)b * 2048 + sc * 64) * 1024 + t * 4;
  for (int s = 0; s < 64; ++s) {
    float wgt = ssc[s];
    if (wgt == 0.f) continue;
    uint2 pk = *(const uint2*)(cp0 + (long)s * 1024);
    acc0 += wgt * __uint_as_float(pk.x << 16);
    acc1 += wgt * __uint_as_float(pk.x & 0xffff0000u);
    acc2 += wgt * __uint_as_float(pk.y << 16);
    acc3 += wgt * __uint_as_float(pk.y & 0xffff0000u);
  }
  float* pp = part + ((long)(b * 32 + sc)) * 1024 + t * 4;
  pp[0] = acc0; pp[1] = acc1; pp[2] = acc2; pp[3] = acc3;
}

// ---------------- K6: reduce wc partials -------------------------------------
__global__ __launch_bounds__(256) void wc_reduce_kernel(
    const float* __restrict__ part, float* __restrict__ wc) {
  int id = blockIdx.x * 256 + threadIdx.x;  // 0..32767
  int b = id >> 10, a = id & 1023;
  float s = 0.f;
#pragma unroll
  for (int scn = 0; scn < 32; ++scn)
    s += part[((long)(b * 32 + scn)) * 1024 + a];
  wc[id] = s;
}

extern "C" void kernel_launch(void* const* d_in, const int* in_sizes, int n_in,
                              void* d_out, int out_size, void* d_ws, size_t ws_size,
                              hipStream_t stream) {
  const float* input   = (const float*)d_in[0];  // 32*1024
  const float* context = (const float*)d_in[1];  // 32*2048*1024
  const float* W_pre   = (const float*)d_in[2];  // 1024*1024
  const float* b_pre   = (const float*)d_in[3];  // 1024
  const float* W_q     = (const float*)d_in[4];  // 1024*1024
  const float* v       = (const float*)d_in[5];  // 1024
  const int*   mask    = (const int*)d_in[6];    // 32*2048

  float* out       = (float*)d_out;
  float* out_wc    = out;                  // 32*1024
  float* out_score = out + 32768;          // 32*2048
  float* out_pre   = out + 98304;          // 32*2048*1024

  // workspace layout (bytes)
  const size_t OFF_CTX   = 0;           // 64M bf16 = 134217728
  const size_t OFF_WPRE  = 134217728;   // 1M bf16  = 2097152
  const size_t OFF_TT    = 136314880;   // 32768 f32 = 131072
  const size_t OFF_EPART = 136445952;   // 65536*16 f32 = 4194304
  const size_t OFF_WCP   = 140640256;   // 32*32*1024 f32 = 4194304
  const size_t WS_NEED   = 144834560;
  if (ws_size < WS_NEED) return;  // fail visibly rather than corrupt

  char* ws = (char*)d_ws;
  unsigned short* ctx_bf  = (unsigned short*)(ws + OFF_CTX);
  unsigned short* wpre_bf = (unsigned short*)(ws + OFF_WPRE);
  float* tT     = (float*)(ws + OFF_TT);
  float* epart  = (float*)(ws + OFF_EPART);
  float* wcpart = (float*)(ws + OFF_WCP);

  convert_bf16_kernel<<<2048, 256, 0, stream>>>(context, ctx_bf, 64LL * 1024 * 1024);
  convert_bf16_kernel<<<256, 256, 0, stream>>>(W_pre, wpre_bf, 1024LL * 1024);
  targetT_kernel<<<128, 256, 0, stream>>>(input, W_q, tT);
  gemm_energy_kernel<<<1024, 512, 0, stream>>>(ctx_bf, wpre_bf, b_pre, tT, v,
                                               out_pre, epart);
  softmax_kernel<<<32, 256, 0, stream>>>(epart, mask, out_score);
  dim3 g5(32, 32);
  wc_partial_kernel<<<g5, 256, 0, stream>>>(ctx_bf, out_score, wcpart);
  wc_reduce_kernel<<<128, 256, 0, stream>>>(wcpart, out_wc);
}

// Round 11
// 369.096 us; speedup vs baseline: 4.6255x; 4.6255x over previous
//
#include <hip/hip_runtime.h>

#define NEG_INF_VAL -1000000.0f

typedef short s16x8 __attribute__((ext_vector_type(8)));
typedef float f32x4 __attribute__((ext_vector_type(4)));

__device__ __forceinline__ unsigned int bf16_rne(float f) {
  unsigned int u = __float_as_uint(f);
  return (u + 0x7fffu + ((u >> 16) & 1u)) >> 16;
}
__device__ __forceinline__ unsigned int pack_bf2(float a, float b) {
  return bf16_rne(a) | (bf16_rne(b) << 16);
}

// tanh(x) = 1 - 2/(e^2x + 1); saturates correctly for |x| large.
__device__ __forceinline__ float fast_tanh(float x) {
  float t = __expf(2.f * x);
  return 1.f - __fdividef(2.f, t + 1.f);
}

// ---------------- K1: fp32 -> bf16 convert (vectorized, grid-stride) ---------
__global__ __launch_bounds__(256) void convert_bf16_kernel(
    const float* __restrict__ src, unsigned short* __restrict__ dst, long n) {
  long i = ((long)blockIdx.x * blockDim.x + threadIdx.x) * 8;
  long stride = (long)gridDim.x * blockDim.x * 8;
  for (; i < n; i += stride) {
    float4 f0 = *(const float4*)(src + i);
    float4 f1 = *(const float4*)(src + i + 4);
    uint4 o;
    o.x = pack_bf2(f0.x, f0.y);
    o.y = pack_bf2(f0.z, f0.w);
    o.z = pack_bf2(f1.x, f1.y);
    o.w = pack_bf2(f1.z, f1.w);
    *(uint4*)(dst + i) = o;
  }
}

// ---------------- K2: targetT[b,d] = sum_q input[b,q] * W_q[d,q] -------------
__global__ __launch_bounds__(256) void targetT_kernel(
    const float* __restrict__ input, const float* __restrict__ Wq,
    float* __restrict__ tT) {
  int d0 = blockIdx.x * 8;
  int t = threadIdx.x;
  int b = t >> 3, dl = t & 7;
  __shared__ float in_s[32][32];
  __shared__ float wq_s[8][32];
  float acc = 0.f;
  for (int q0 = 0; q0 < 1024; q0 += 32) {
    int r = t >> 3, c = (t & 7) * 4;
    *(float4*)&in_s[r][c] = *(const float4*)&input[r * 1024 + q0 + c];
    wq_s[t >> 5][t & 31] = Wq[(long)(d0 + (t >> 5)) * 1024 + q0 + (t & 31)];
    __syncthreads();
#pragma unroll
    for (int qq = 0; qq < 32; ++qq)
      acc += in_s[b][qq] * wq_s[dl][qq];
    __syncthreads();
  }
  tT[b * 1024 + d0 + dl] = acc;
}

// ---------------- K3: big GEMM + fused bias/tanh/energy-partial epilogue -----
// C[m,d] = sum_a ctx_bf16[m,a] * Wpre_bf16[d,a]  (NT GEMM)
// Block tile 256(M)x128(N), BK=32, 4 waves (2Mx2N, wave-tile 128x64 --
// IDENTICAL per-wave geometry to the 193us R8 kernel), LDS 48 KiB ->
// 2 INDEPENDENT blocks/CU (~210 regs < 256 at launch_bounds(256,2)).
// Sibling block on its own barrier schedule fills this block's vmcnt(0)
// drain, prologue, and epilogue stalls (m114 co-scheduling).
__device__ __forceinline__ void load_lds16(const void* g, void* l) {
  __builtin_amdgcn_global_load_lds(
      (const __attribute__((address_space(1))) void*)g,
      (__attribute__((address_space(3))) void*)l, 16, 0, 0);
}

// Stage A [256][32] + B [128][32] granules of K-tile SKT into buf SB.
// LDS byte layout: A0 @0 (16K), B0 @16384 (8K), A1 @24576, B1 @40960.
#define STAGE_T(SB, SKT)                                                             \
  {                                                                                  \
    const unsigned short* gpA = Ag + (SKT) * 32;                                     \
    const unsigned short* gpB = Bg + (SKT) * 32;                                     \
    char* lpA = dstB + (SB) * 24576;                                                 \
    char* lpB = lpA + 16384;                                                         \
    load_lds16(gpA,               lpA);                                              \
    load_lds16(gpA +  64 * 1024,  lpA + 4096);                                       \
    load_lds16(gpA + 128L * 1024, lpA + 8192);                                       \
    load_lds16(gpA + 192L * 1024, lpA + 12288);                                      \
    load_lds16(gpB,               lpB);                                              \
    load_lds16(gpB +  64 * 1024,  lpB + 4096);                                       \
  }

#define MFMA_ROW(I, AF)                                                              \
  acc[I][0] = __builtin_amdgcn_mfma_f32_16x16x32_bf16(AF, bf[0], acc[I][0], 0, 0, 0);\
  acc[I][1] = __builtin_amdgcn_mfma_f32_16x16x32_bf16(AF, bf[1], acc[I][1], 0, 0, 0);\
  acc[I][2] = __builtin_amdgcn_mfma_f32_16x16x32_bf16(AF, bf[2], acc[I][2], 0, 0, 0);\
  acc[I][3] = __builtin_amdgcn_mfma_f32_16x16x32_bf16(AF, bf[3], acc[I][3], 0, 0, 0);

// One K-tile: read 8 A-frags + 4 B-frags from buf BUF, stage tile SKT into
// buf SB, 32 MFMA, drain DMA, barrier. (Proven R10 structure, no spill now.)
#define TILE(BUF, SB, SKT)                                                           \
  {                                                                                  \
    const unsigned short* pA = (BUF) ? pA1 : pA0;                                    \
    const unsigned short* pB = (BUF) ? pB1 : pB0;                                    \
    s16x8 af[8], bf[4];                                                              \
    _Pragma("unroll")                                                                \
    for (int i = 0; i < 8; ++i) af[i] = *(const s16x8*)(pA + i * 512);               \
    _Pragma("unroll")                                                                \
    for (int j = 0; j < 4; ++j) bf[j] = *(const s16x8*)(pB + j * 512);               \
    STAGE_T(SB, SKT)                                                                 \
    __builtin_amdgcn_s_setprio(1);                                                   \
    MFMA_ROW(0, af[0]) MFMA_ROW(1, af[1]) MFMA_ROW(2, af[2]) MFMA_ROW(3, af[3])      \
    MFMA_ROW(4, af[4]) MFMA_ROW(5, af[5]) MFMA_ROW(6, af[6]) MFMA_ROW(7, af[7])      \
    __builtin_amdgcn_s_setprio(0);                                                   \
    asm volatile("s_waitcnt vmcnt(0)");                                              \
    __builtin_amdgcn_sched_barrier(0);                                               \
    __builtin_amdgcn_s_barrier();                                                    \
  }

__global__ __launch_bounds__(256, 2) void gemm_energy_kernel(
    const unsigned short* __restrict__ A,   // [65536][1024] bf16
    const unsigned short* __restrict__ Bm,  // [1024][1024] bf16 (W_pre, N x K)
    const float* __restrict__ b_pre,        // [1024]
    const float* __restrict__ tT,           // [32][1024]
    const float* __restrict__ vvec,         // [1024]
    float* __restrict__ Cout,               // precompute [65536][1024] fp32
    float* __restrict__ epart) {            // [65536][16] fp32 partial energies
  // XCD-aware swizzle: nwg=2048 (%8==0); nt fastest within an XCD chunk so
  // the 8 nt-blocks sharing an A-panel are co-resident on one XCD's L2.
  int lin = blockIdx.x;
  int w = (lin & 7) * 256 + (lin >> 3);
  int nt = w & 7;                          // 0..7   (N tiles of 128)
  int mt = w >> 3;                         // 0..255 (M tiles of 256)
  int m0 = mt * 256, n0 = nt * 128;
  int tid = threadIdx.x;
  int lane = tid & 63, wid = tid >> 6;     // 4 waves
  int wr = wid >> 1, wc = wid & 1;         // 2 x 2
  int r = lane & 15, g = lane >> 4;

  // flat LDS: 49152 B = A0(16K) B0(8K) A1(16K) B1(8K)
  __shared__ unsigned short sMem[24576];

  f32x4 acc[8][4] = {};

  // read-side swizzled 16B slot (element offset): phys = g ^ ((r>>1)&3)
  int physoff = (g ^ ((r >> 1) & 3)) * 8;

  // LDS read bases (element offsets); per-tile frag offsets are imms.
  int aoffe = (wr * 128 + r) * 32 + physoff;
  int boffe = (wc * 64 + r) * 32 + physoff;
  const unsigned short* pA0 = sMem + aoffe;            // byte 0
  const unsigned short* pB0 = sMem + 8192 + boffe;     // byte 16384
  const unsigned short* pA1 = sMem + 12288 + aoffe;    // byte 24576
  const unsigned short* pB1 = sMem + 20480 + boffe;    // byte 40960
  char* dstB = (char*)sMem + wid * 1024;   // linear gload_lds dest slice

  // staging source: inst i covers rows i*64 + wid*16 + (lane>>2); global col
  // pre-swizzled: physical slot (lane&3) holds logical (lane&3)^((lane>>3)&3).
  int srow = wid * 16 + (lane >> 2);
  int slog8 = ((lane & 3) ^ ((lane >> 3) & 3)) * 8;
  const unsigned short* Ag = A + (long)(m0 + srow) * 1024 + slog8;
  const unsigned short* Bg = Bm + (long)(n0 + srow) * 1024 + slog8;

  // ---- prologue: buf0 = tile 0 ----
  STAGE_T(0, 0)
  asm volatile("s_waitcnt vmcnt(0)");
  __builtin_amdgcn_sched_barrier(0);
  __builtin_amdgcn_s_barrier();

  // ---- main loop: 32 K-tiles, 2 per iter (literal buf indices) ----
#pragma unroll 1
  for (int t0 = 0; t0 < 30; t0 += 2) {
    TILE(0, 1, t0 + 1)   // compute tile t0 (buf0); stage t0+1 -> buf1
    TILE(1, 0, t0 + 2)   // compute tile t0+1 (buf1); stage t0+2 -> buf0
  }
  TILE(0, 1, 31)         // compute tile 30; stage tile 31 -> buf1
  TILE(1, 0, 31)         // compute tile 31; re-stage 31 (unused, in-bounds)

  // ---- epilogue: C = acc + b_pre; energy partial = sum_d tanh(C+tT)*v ----
  int b = m0 >> 11;  // 256 | 2048 -> batch uniform per block
  float bias[4], tv[4], vv[4];
#pragma unroll
  for (int j = 0; j < 4; ++j) {
    int d = n0 + wc * 64 + j * 16 + r;
    bias[j] = b_pre[d];
    tv[j] = tT[b * 1024 + d];
    vv[j] = vvec[d];
  }
#pragma unroll
  for (int i = 0; i < 8; ++i) {
#pragma unroll
    for (int q = 0; q < 4; ++q) {
      int m = m0 + wr * 128 + i * 16 + g * 4 + q;
      float e = 0.f;
#pragma unroll
      for (int j = 0; j < 4; ++j) {
        float val = acc[i][j][q] + bias[j];
        Cout[(long)m * 1024 + n0 + wc * 64 + j * 16 + r] = val;
        e += fast_tanh(val + tv[j]) * vv[j];
      }
      e += __shfl_xor(e, 1);
      e += __shfl_xor(e, 2);
      e += __shfl_xor(e, 4);
      e += __shfl_xor(e, 8);
      if (r == 0) epart[(long)m * 16 + nt * 2 + wc] = e;
    }
  }
}

// ---------------- K4: reduce partials, mask, softmax over S ------------------
__global__ __launch_bounds__(256) void softmax_kernel(
    const float* __restrict__ epart, const int* __restrict__ mask,
    float* __restrict__ score) {
  int b = blockIdx.x;
  int t = threadIdx.x;
  __shared__ float red[256];
  float ev[8];
  float mx = -3.4e38f;
#pragma unroll
  for (int ii = 0; ii < 8; ++ii) {
    int s = ii * 256 + t;
    long m = (long)b * 2048 + s;
    const float4* p = (const float4*)(epart + m * 16);
    float4 p0 = p[0], p1 = p[1], p2 = p[2], p3 = p[3];
    float e = p0.x + p0.y + p0.z + p0.w + p1.x + p1.y + p1.z + p1.w
            + p2.x + p2.y + p2.z + p2.w + p3.x + p3.y + p3.z + p3.w;
    if (mask[b * 2048 + s] == 0) e = NEG_INF_VAL;
    ev[ii] = e;
    mx = fmaxf(mx, e);
  }
  red[t] = mx; __syncthreads();
  for (int off = 128; off > 0; off >>= 1) {
    if (t < off) red[t] = fmaxf(red[t], red[t + off]);
    __syncthreads();
  }
  mx = red[0];
  __syncthreads();
  float sum = 0.f;
#pragma unroll
  for (int ii = 0; ii < 8; ++ii) { ev[ii] = __expf(ev[ii] - mx); sum += ev[ii]; }
  red[t] = sum; __syncthreads();
  for (int off = 128; off > 0; off >>= 1) {
    if (t < off) red[t] += red[t + off];
    __syncthreads();
  }
  float inv = 1.f / red[0];
#pragma unroll
  for (int ii = 0; ii < 8; ++ii)
    score[b * 2048 + ii * 256 + t] = ev[ii] * inv;
}

// ---------------- K5: weightedContext partials over s-chunks -----------------
// Masked rows have score EXACTLY 0 (exp underflow) -> skip their 2KB read.
__global__ __launch_bounds__(256) void wc_partial_kernel(
    const unsigned short* __restrict__ ctx, const float* __restrict__ score,
    float* __restrict__ part) {
  int b = blockIdx.x, sc = blockIdx.y;
  int t = threadIdx.x;
  __shared__ float ssc[64];
  if (t < 64) ssc[t] = score[b * 2048 + sc * 64 + t];
  __syncthreads();
  float acc0 = 0.f, acc1 = 0.f, acc2 = 0.f, acc3 = 0.f;
  const unsigned short* cp0 = ctx + ((long)b * 2048 + sc * 64) * 1024 + t * 4;
  for (int s = 0; s < 64; ++s) {
    float wgt = ssc[s];
    if (wgt == 0.f) continue;
    uint2 pk = *(const uint2*)(cp0 + (long)s * 1024);
    acc0 += wgt * __uint_as_float(pk.x << 16);
    acc1 += wgt * __uint_as_float(pk.x & 0xffff0000u);
    acc2 += wgt * __uint_as_float(pk.y << 16);
    acc3 += wgt * __uint_as_float(pk.y & 0xffff0000u);
  }
  float* pp = part + ((long)(b * 32 + sc)) * 1024 + t * 4;
  pp[0] = acc0; pp[1] = acc1; pp[2] = acc2; pp[3] = acc3;
}

// ---------------- K6: reduce wc partials -------------------------------------
__global__ __launch_bounds__(256) void wc_reduce_kernel(
    const float* __restrict__ part, float* __restrict__ wc) {
  int id = blockIdx.x * 256 + threadIdx.x;  // 0..32767
  int b = id >> 10, a = id & 1023;
  float s = 0.f;
#pragma unroll
  for (int scn = 0; scn < 32; ++scn)
    s += part[((long)(b * 32 + scn)) * 1024 + a];
  wc[id] = s;
}

extern "C" void kernel_launch(void* const* d_in, const int* in_sizes, int n_in,
                              void* d_out, int out_size, void* d_ws, size_t ws_size,
                              hipStream_t stream) {
  const float* input   = (const float*)d_in[0];  // 32*1024
  const float* context = (const float*)d_in[1];  // 32*2048*1024
  const float* W_pre   = (const float*)d_in[2];  // 1024*1024
  const float* b_pre   = (const float*)d_in[3];  // 1024
  const float* W_q     = (const float*)d_in[4];  // 1024*1024
  const float* v       = (const float*)d_in[5];  // 1024
  const int*   mask    = (const int*)d_in[6];    // 32*2048

  float* out       = (float*)d_out;
  float* out_wc    = out;                  // 32*1024
  float* out_score = out + 32768;          // 32*2048
  float* out_pre   = out + 98304;          // 32*2048*1024

  // workspace layout (bytes)
  const size_t OFF_CTX   = 0;           // 64M bf16 = 134217728
  const size_t OFF_WPRE  = 134217728;   // 1M bf16  = 2097152
  const size_t OFF_TT    = 136314880;   // 32768 f32 = 131072
  const size_t OFF_EPART = 136445952;   // 65536*16 f32 = 4194304
  const size_t OFF_WCP   = 140640256;   // 32*32*1024 f32 = 4194304
  const size_t WS_NEED   = 144834560;
  if (ws_size < WS_NEED) return;  // fail visibly rather than corrupt

  char* ws = (char*)d_ws;
  unsigned short* ctx_bf  = (unsigned short*)(ws + OFF_CTX);
  unsigned short* wpre_bf = (unsigned short*)(ws + OFF_WPRE);
  float* tT     = (float*)(ws + OFF_TT);
  float* epart  = (float*)(ws + OFF_EPART);
  float* wcpart = (float*)(ws + OFF_WCP);

  convert_bf16_kernel<<<2048, 256, 0, stream>>>(context, ctx_bf, 64LL * 1024 * 1024);
  convert_bf16_kernel<<<256, 256, 0, stream>>>(W_pre, wpre_bf, 1024LL * 1024);
  targetT_kernel<<<128, 256, 0, stream>>>(input, W_q, tT);
  gemm_energy_kernel<<<2048, 256, 0, stream>>>(ctx_bf, wpre_bf, b_pre, tT, v,
                                               out_pre, epart);
  softmax_kernel<<<32, 256, 0, stream>>>(epart, mask, out_score);
  dim3 g5(32, 32);
  wc_partial_kernel<<<g5, 256, 0, stream>>>(ctx_bf, out_score, wcpart);
  wc_reduce_kernel<<<128, 256, 0, stream>>>(wcpart, out_wc);
}

// Round 12
// 345.533 us; speedup vs baseline: 4.9409x; 1.0682x over previous
//
#include <hip/hip_runtime.h>

#define NEG_INF_VAL -1000000.0f

typedef short s16x8 __attribute__((ext_vector_type(8)));
typedef float f32x4 __attribute__((ext_vector_type(4)));

__device__ __forceinline__ unsigned int bf16_rne(float f) {
  unsigned int u = __float_as_uint(f);
  return (u + 0x7fffu + ((u >> 16) & 1u)) >> 16;
}
__device__ __forceinline__ unsigned int pack_bf2(float a, float b) {
  return bf16_rne(a) | (bf16_rne(b) << 16);
}

// tanh(x) = 1 - 2/(e^2x + 1); saturates correctly for |x| large.
__device__ __forceinline__ float fast_tanh(float x) {
  float t = __expf(2.f * x);
  return 1.f - __fdividef(2.f, t + 1.f);
}

// ---------------- K1: fp32 -> bf16 convert (vectorized, grid-stride) ---------
__global__ __launch_bounds__(256) void convert_bf16_kernel(
    const float* __restrict__ src, unsigned short* __restrict__ dst, long n) {
  long i = ((long)blockIdx.x * blockDim.x + threadIdx.x) * 8;
  long stride = (long)gridDim.x * blockDim.x * 8;
  for (; i < n; i += stride) {
    float4 f0 = *(const float4*)(src + i);
    float4 f1 = *(const float4*)(src + i + 4);
    uint4 o;
    o.x = pack_bf2(f0.x, f0.y);
    o.y = pack_bf2(f0.z, f0.w);
    o.z = pack_bf2(f1.x, f1.y);
    o.w = pack_bf2(f1.z, f1.w);
    *(uint4*)(dst + i) = o;
  }
}

// ---------------- K2: targetT[b,d] = sum_q input[b,q] * W_q[d,q] -------------
__global__ __launch_bounds__(256) void targetT_kernel(
    const float* __restrict__ input, const float* __restrict__ Wq,
    float* __restrict__ tT) {
  int d0 = blockIdx.x * 8;
  int t = threadIdx.x;
  int b = t >> 3, dl = t & 7;
  __shared__ float in_s[32][32];
  __shared__ float wq_s[8][32];
  float acc = 0.f;
  for (int q0 = 0; q0 < 1024; q0 += 32) {
    int r = t >> 3, c = (t & 7) * 4;
    *(float4*)&in_s[r][c] = *(const float4*)&input[r * 1024 + q0 + c];
    wq_s[t >> 5][t & 31] = Wq[(long)(d0 + (t >> 5)) * 1024 + q0 + (t & 31)];
    __syncthreads();
#pragma unroll
    for (int qq = 0; qq < 32; ++qq)
      acc += in_s[b][qq] * wq_s[dl][qq];
    __syncthreads();
  }
  tT[b * 1024 + d0 + dl] = acc;
}

// ---------------- K3: big GEMM + fused bias/tanh/energy-partial epilogue -----
// C[m,d] = sum_a ctx_bf16[m,a] * Wpre_bf16[d,a]  (NT GEMM)
// R8 structure (best measured: 193us): 256x256 tile, BK=32, 8 waves (2Mx4N,
// wave-tile 128x64), LDS 64 KiB, per-tile {frag reads | stage next | 32 MFMA |
// vmcnt(0) | barrier}. Epilogue stores are NON-TEMPORAL (256 MB streaming,
// never re-read) to keep A-panels/W_pre L2-resident.
__device__ __forceinline__ void load_lds16(const void* g, void* l) {
  __builtin_amdgcn_global_load_lds(
      (const __attribute__((address_space(1))) void*)g,
      (__attribute__((address_space(3))) void*)l, 16, 0, 0);
}

// Stage A+B granules ([256 rows][32 cols] bf16 each) of K-tile SKT into buf SB.
#define STAGE_T(SB, SKT)                                                             \
  {                                                                                  \
    const unsigned short* gpA = Ag + (SKT) * 32;                                     \
    const unsigned short* gpB = Bg + (SKT) * 32;                                     \
    char* lp = dstB + (SB) * 32768;                                                  \
    load_lds16(gpA, lp);                                                             \
    load_lds16(gpA + 128L * 1024, lp + 8192);                                        \
    load_lds16(gpB, lp + 16384);                                                     \
    load_lds16(gpB + 128L * 1024, lp + 16384 + 8192);                                \
  }

#define MFMA_ROW(I, AF)                                                              \
  acc[I][0] = __builtin_amdgcn_mfma_f32_16x16x32_bf16(AF, bf[0], acc[I][0], 0, 0, 0);\
  acc[I][1] = __builtin_amdgcn_mfma_f32_16x16x32_bf16(AF, bf[1], acc[I][1], 0, 0, 0);\
  acc[I][2] = __builtin_amdgcn_mfma_f32_16x16x32_bf16(AF, bf[2], acc[I][2], 0, 0, 0);\
  acc[I][3] = __builtin_amdgcn_mfma_f32_16x16x32_bf16(AF, bf[3], acc[I][3], 0, 0, 0);

// One K-tile: read 8 A-frags + 4 B-frags from buf BUF, stage tile SKT into
// buf SB, 32 MFMA, drain DMA, barrier.
#define TILE(BUF, SB, SKT)                                                           \
  {                                                                                  \
    const unsigned short* pA = (BUF) ? pA1 : pA0;                                    \
    const unsigned short* pB = (BUF) ? pB1 : pB0;                                    \
    s16x8 af[8], bf[4];                                                              \
    _Pragma("unroll")                                                                \
    for (int i = 0; i < 8; ++i) af[i] = *(const s16x8*)(pA + i * 512);               \
    _Pragma("unroll")                                                                \
    for (int j = 0; j < 4; ++j) bf[j] = *(const s16x8*)(pB + j * 512);               \
    STAGE_T(SB, SKT)                                                                 \
    __builtin_amdgcn_s_setprio(1);                                                   \
    MFMA_ROW(0, af[0]) MFMA_ROW(1, af[1]) MFMA_ROW(2, af[2]) MFMA_ROW(3, af[3])      \
    MFMA_ROW(4, af[4]) MFMA_ROW(5, af[5]) MFMA_ROW(6, af[6]) MFMA_ROW(7, af[7])      \
    __builtin_amdgcn_s_setprio(0);                                                   \
    asm volatile("s_waitcnt vmcnt(0)");                                              \
    __builtin_amdgcn_sched_barrier(0);                                               \
    __builtin_amdgcn_s_barrier();                                                    \
  }

__global__ __launch_bounds__(512, 2) void gemm_energy_kernel(
    const unsigned short* __restrict__ A,   // [65536][1024] bf16
    const unsigned short* __restrict__ Bm,  // [1024][1024] bf16 (W_pre, N x K)
    const float* __restrict__ b_pre,        // [1024]
    const float* __restrict__ tT,           // [32][1024]
    const float* __restrict__ vvec,         // [1024]
    float* __restrict__ Cout,               // precompute [65536][1024] fp32
    float* __restrict__ epart) {            // [65536][16] fp32 partial energies
  // XCD-aware swizzle: nwg=1024 (%8==0); nt fastest within an XCD chunk.
  int lin = blockIdx.x;
  int w = (lin & 7) * 128 + (lin >> 3);
  int nt = w & 3;
  int mt = w >> 2;
  int m0 = mt * 256, n0 = nt * 256;
  int tid = threadIdx.x;
  int lane = tid & 63, wid = tid >> 6;     // 8 waves
  int wr = wid >> 2, wc = wid & 3;         // 2 x 4
  int r = lane & 15, g = lane >> 4;

  // flat LDS: [buf][mat][256 rows][32 cols] bf16 = 64 KiB
  __shared__ unsigned short sMem[2 * 2 * 256 * 32];

  f32x4 acc[8][4] = {};

  // read-side swizzled 16B slot (element offset): phys = g ^ ((r>>1)&3)
  int physoff = (g ^ ((r >> 1) & 3)) * 8;

  // LDS read bases; per-tile frag offsets are compile-time immediates.
  int aoffe = (wr * 128 + r) * 32 + physoff;
  int boffe = (wc * 64 + r) * 32 + physoff;
  const unsigned short* pA0 = sMem + aoffe;
  const unsigned short* pB0 = sMem + 8192 + boffe;
  const unsigned short* pA1 = sMem + 16384 + aoffe;
  const unsigned short* pB1 = sMem + 24576 + boffe;
  char* dstB = (char*)sMem + wid * 1024;   // linear gload_lds dest slice

  // staging source: thread covers rows {tid>>2, tid>>2+128}; global col
  // pre-swizzled: physical slot (tid&3) holds logical (tid&3)^((tid>>3)&3).
  int srow = tid >> 2;
  int slog8 = ((tid & 3) ^ ((tid >> 3) & 3)) * 8;
  const unsigned short* Ag = A + (long)(m0 + srow) * 1024 + slog8;
  const unsigned short* Bg = Bm + (long)(n0 + srow) * 1024 + slog8;

  // ---- prologue: buf0 = tile 0 ----
  STAGE_T(0, 0)
  asm volatile("s_waitcnt vmcnt(0)");
  __builtin_amdgcn_sched_barrier(0);
  __builtin_amdgcn_s_barrier();

  // ---- main loop: 32 K-tiles, 2 per iter (literal buf indices) ----
#pragma unroll 1
  for (int t0 = 0; t0 < 30; t0 += 2) {
    TILE(0, 1, t0 + 1)   // compute tile t0 (buf0); stage t0+1 -> buf1
    TILE(1, 0, t0 + 2)   // compute tile t0+1 (buf1); stage t0+2 -> buf0
  }
  TILE(0, 1, 31)         // compute tile 30; stage tile 31 -> buf1
  TILE(1, 0, 31)         // compute tile 31; re-stage 31 (unused, in-bounds)

  // ---- epilogue: C = acc + b_pre; energy partial = sum_d tanh(C+tT)*v ----
  int b = m0 >> 11;  // 256 | 2048 -> batch uniform per block
  float bias[4], tv[4], vv[4];
#pragma unroll
  for (int j = 0; j < 4; ++j) {
    int d = n0 + wc * 64 + j * 16 + r;
    bias[j] = b_pre[d];
    tv[j] = tT[b * 1024 + d];
    vv[j] = vvec[d];
  }
#pragma unroll
  for (int i = 0; i < 8; ++i) {
#pragma unroll
    for (int q = 0; q < 4; ++q) {
      int m = m0 + wr * 128 + i * 16 + g * 4 + q;
      float e = 0.f;
#pragma unroll
      for (int j = 0; j < 4; ++j) {
        float val = acc[i][j][q] + bias[j];
        __builtin_nontemporal_store(val,
            &Cout[(long)m * 1024 + n0 + wc * 64 + j * 16 + r]);
        e += fast_tanh(val + tv[j]) * vv[j];
      }
      e += __shfl_xor(e, 1);
      e += __shfl_xor(e, 2);
      e += __shfl_xor(e, 4);
      e += __shfl_xor(e, 8);
      if (r == 0) epart[(long)m * 16 + nt * 4 + wc] = e;
    }
  }
}

// ---------------- K4: reduce partials, mask, softmax over S ------------------
__global__ __launch_bounds__(256) void softmax_kernel(
    const float* __restrict__ epart, const int* __restrict__ mask,
    float* __restrict__ score) {
  int b = blockIdx.x;
  int t = threadIdx.x;
  __shared__ float red[256];
  float ev[8];
  float mx = -3.4e38f;
#pragma unroll
  for (int ii = 0; ii < 8; ++ii) {
    int s = ii * 256 + t;
    long m = (long)b * 2048 + s;
    const float4* p = (const float4*)(epart + m * 16);
    float4 p0 = p[0], p1 = p[1], p2 = p[2], p3 = p[3];
    float e = p0.x + p0.y + p0.z + p0.w + p1.x + p1.y + p1.z + p1.w
            + p2.x + p2.y + p2.z + p2.w + p3.x + p3.y + p3.z + p3.w;
    if (mask[b * 2048 + s] == 0) e = NEG_INF_VAL;
    ev[ii] = e;
    mx = fmaxf(mx, e);
  }
  red[t] = mx; __syncthreads();
  for (int off = 128; off > 0; off >>= 1) {
    if (t < off) red[t] = fmaxf(red[t], red[t + off]);
    __syncthreads();
  }
  mx = red[0];
  __syncthreads();
  float sum = 0.f;
#pragma unroll
  for (int ii = 0; ii < 8; ++ii) { ev[ii] = __expf(ev[ii] - mx); sum += ev[ii]; }
  red[t] = sum; __syncthreads();
  for (int off = 128; off > 0; off >>= 1) {
    if (t < off) red[t] += red[t + off];
    __syncthreads();
  }
  float inv = 1.f / red[0];
#pragma unroll
  for (int ii = 0; ii < 8; ++ii)
    score[b * 2048 + ii * 256 + t] = ev[ii] * inv;
}

// ---------------- K5: weightedContext partials over s-chunks -----------------
// Masked rows have score EXACTLY 0 (exp underflow) -> skip their 2KB read.
// wgt is uniform across the block for a given s => wave-uniform branch.
__global__ __launch_bounds__(256) void wc_partial_kernel(
    const unsigned short* __restrict__ ctx, const float* __restrict__ score,
    float* __restrict__ part) {
  int b = blockIdx.x, sc = blockIdx.y;
  int t = threadIdx.x;
  __shared__ float ssc[64];
  if (t < 64) ssc[t] = score[b * 2048 + sc * 64 + t];
  __syncthreads();
  float acc0 = 0.f, acc1 = 0.f, acc2 = 0.f, acc3 = 0.f;
  const unsigned short* cp0 = ctx + ((long)b * 2048 + sc * 64) * 1024 + t * 4;
  for (int s = 0; s < 64; ++s) {
    float wgt = ssc[s];
    if (wgt == 0.f) continue;
    uint2 pk = *(const uint2*)(cp0 + (long)s * 1024);
    acc0 += wgt * __uint_as_float(pk.x << 16);
    acc1 += wgt * __uint_as_float(pk.x & 0xffff0000u);
    acc2 += wgt * __uint_as_float(pk.y << 16);
    acc3 += wgt * __uint_as_float(pk.y & 0xffff0000u);
  }
  float* pp = part + ((long)(b * 32 + sc)) * 1024 + t * 4;
  pp[0] = acc0; pp[1] = acc1; pp[2] = acc2; pp[3] = acc3;
}

// ---------------- K6: reduce wc partials -------------------------------------
__global__ __launch_bounds__(256) void wc_reduce_kernel(
    const float* __restrict__ part, float* __restrict__ wc) {
  int id = blockIdx.x * 256 + threadIdx.x;  // 0..32767
  int b = id >> 10, a = id & 1023;
  float s = 0.f;
#pragma unroll
  for (int scn = 0; scn < 32; ++scn)
    s += part[((long)(b * 32 + scn)) * 1024 + a];
  wc[id] = s;
}

extern "C" void kernel_launch(void* const* d_in, const int* in_sizes, int n_in,
                              void* d_out, int out_size, void* d_ws, size_t ws_size,
                              hipStream_t stream) {
  const float* input   = (const float*)d_in[0];  // 32*1024
  const float* context = (const float*)d_in[1];  // 32*2048*1024
  const float* W_pre   = (const float*)d_in[2];  // 1024*1024
  const float* b_pre   = (const float*)d_in[3];  // 1024
  const float* W_q     = (const float*)d_in[4];  // 1024*1024
  const float* v       = (const float*)d_in[5];  // 1024
  const int*   mask    = (const int*)d_in[6];    // 32*2048

  float* out       = (float*)d_out;
  float* out_wc    = out;                  // 32*1024
  float* out_score = out + 32768;          // 32*2048
  float* out_pre   = out + 98304;          // 32*2048*1024

  // workspace layout (bytes)
  const size_t OFF_CTX   = 0;           // 64M bf16 = 134217728
  const size_t OFF_WPRE  = 134217728;   // 1M bf16  = 2097152
  const size_t OFF_TT    = 136314880;   // 32768 f32 = 131072
  const size_t OFF_EPART = 136445952;   // 65536*16 f32 = 4194304
  const size_t OFF_WCP   = 140640256;   // 32*32*1024 f32 = 4194304
  const size_t WS_NEED   = 144834560;
  if (ws_size < WS_NEED) return;  // fail visibly rather than corrupt

  char* ws = (char*)d_ws;
  unsigned short* ctx_bf  = (unsigned short*)(ws + OFF_CTX);
  unsigned short* wpre_bf = (unsigned short*)(ws + OFF_WPRE);
  float* tT     = (float*)(ws + OFF_TT);
  float* epart  = (float*)(ws + OFF_EPART);
  float* wcpart = (float*)(ws + OFF_WCP);

  convert_bf16_kernel<<<2048, 256, 0, stream>>>(context, ctx_bf, 64LL * 1024 * 1024);
  convert_bf16_kernel<<<256, 256, 0, stream>>>(W_pre, wpre_bf, 1024LL * 1024);
  targetT_kernel<<<128, 256, 0, stream>>>(input, W_q, tT);
  gemm_energy_kernel<<<1024, 512, 0, stream>>>(ctx_bf, wpre_bf, b_pre, tT, v,
                                               out_pre, epart);
  softmax_kernel<<<32, 256, 0, stream>>>(epart, mask, out_score);
  dim3 g5(32, 32);
  wc_partial_kernel<<<g5, 256, 0, stream>>>(ctx_bf, out_score, wcpart);
  wc_reduce_kernel<<<128, 256, 0, stream>>>(wcpart, out_wc);
}